// Round 13
// baseline (127.808 us; speedup 1.0000x reference)
//
#include <hip/hip_runtime.h>
#include <hip/hip_bf16.h>

// B=2, L=256, D=128, H=256 fast-weight (TTT-style) forward.
// Exact rewrite: sequential momentum/weight-decay scan -> decay-weighted
// attention with composed decay matrix S = wd_cs @ mom_cs via the stable
// O(L^2) recurrence (all exponents <= 0 in the live region).
//
// v13 = v12 with 1024-thread blocks for k_token/k_query: same 2-token tiles
// (reuse preserved) but every dot split 2x more ways across 16 waves/CU
// (4/SIMD, double the latency hiding of v12); partials combine in LDS.

#define Bc 2
#define Lc 256
#define Dc 128
#define Hc 256

__device__ __forceinline__ float sigf(float z)  { return 1.f / (1.f + expf(-z)); }
__device__ __forceinline__ float siluf(float z) { return z * sigf(z); }
// replicates reference silu_backward exactly: s + sigmoid(z)*(1-s), s=silu(z)
__device__ __forceinline__ float silubwdf(float z) {
    float sg = sigf(z);
    float s  = z * sg;
    return s + sg * (1.f - s);
}
__device__ __forceinline__ float softplusf(float z) {
    if (z > 20.f)  return z;
    if (z < -20.f) return expf(z);
    return log1pf(expf(z));
}
__device__ __forceinline__ float dot4(float4 a, float4 b) {
    return a.x*b.x + a.y*b.y + a.z*b.z + a.w*b.w;
}

// ---------------------------------------------------------------------------
// K0: pure weight interleave, 144 blocks x 256 threads.
// ---------------------------------------------------------------------------
__global__ __launch_bounds__(256) void k_pre(
    const float* __restrict__ Wq, const float* __restrict__ Wk,
    const float* __restrict__ Wv, const float* __restrict__ W1,
    const float* __restrict__ W2,
    float4* __restrict__ Wq4, float4* __restrict__ Wk4, float4* __restrict__ Wv4,
    float4* __restrict__ W14, float4* __restrict__ W2q4, float4* __restrict__ W2c4)
{
    const int bb = blockIdx.x;
    if (bb < 112) {
        const float* in; float4* o; int M, N, base;
        if      (bb < 16) { in = Wq; o = Wq4;  M = 128; N = 128; base = 0;  }
        else if (bb < 32) { in = Wk; o = Wk4;  M = 128; N = 128; base = 16; }
        else if (bb < 48) { in = Wv; o = Wv4;  M = 128; N = 128; base = 32; }
        else if (bb < 80) { in = W1; o = W14;  M = 256; N = 128; base = 48; }
        else              { in = W2; o = W2q4; M = 128; N = 256; base = 80; }
        const int idx = (bb - base) * 256 + threadIdx.x;
        const int r = idx % M, g = idx / M;
        o[idx] = *(const float4*)(in + r * N + 4 * g);
    } else {
        const int idx = (bb - 112) * 256 + threadIdx.x;   // 0..8191
        const int c = idx & 255, g = idx >> 8;
        W2c4[idx] = make_float4(W2[(4*g+0)*Hc + c], W2[(4*g+1)*Hc + c],
                                W2[(4*g+2)*Hc + c], W2[(4*g+3)*Hc + c]);
    }
}

// ---------------------------------------------------------------------------
// K1: token fwd + grads (blocks 0..255, 2 tokens/block, 1024 threads) +
//     gate/decay scan (blocks 256/257, one per batch; first 256 threads).
// ---------------------------------------------------------------------------
__global__ __launch_bounds__(1024, 4) void k_token(
    const float* __restrict__ x,
    const float* __restrict__ b1v, const float* __restrict__ b2v,
    const float* __restrict__ bq,  const float* __restrict__ bk,
    const float* __restrict__ bv,
    const float4* __restrict__ Wq4, const float4* __restrict__ Wk4,
    const float4* __restrict__ Wv4, const float4* __restrict__ W14,
    const float4* __restrict__ W2q4, const float4* __restrict__ W2c4,
    const float* __restrict__ Wlr, const float* __restrict__ blr,
    const float* __restrict__ Wm,  const float* __restrict__ bm,
    const float* __restrict__ Wwd, const float* __restrict__ bwd,
    float* __restrict__ qo, float* __restrict__ KT, float* __restrict__ X2T,
    float* __restrict__ z1q, float* __restrict__ GZ1, float* __restrict__ GZ2,
    float* __restrict__ Ssc, float* __restrict__ wdf)
{
    const int bb  = blockIdx.x;
    const int tid = threadIdx.x;

    if (bb >= Bc * Lc / 2) {
        // ================= gate/decay scan (1 block per batch) =============
        __shared__ __align__(16) float lrS[Lc];
        __shared__ __align__(16) float lwS[Lc];
        __shared__ __align__(16) float ewdS[Lc];
        __shared__ __align__(16) float clmS[Lc];
        __shared__ __align__(16) float cwdS[Lc];
        const int b = bb - Bc * Lc / 2;
        const int l = tid;
        if (l < Lc) {
            const float4* xr4 = (const float4*)(x + (b * Lc + l) * Dc);
            const float4* wl4 = (const float4*)Wlr;
            const float4* wm4 = (const float4*)Wm;
            const float4* ww4 = (const float4*)Wwd;
            float dlr = blr[0], dm = bm[0], dw = bwd[0];
            #pragma unroll 4
            for (int j = 0; j < Dc / 4; ++j) {
                float4 xv = xr4[j];
                dlr += dot4(wl4[j], xv);
                dm  += dot4(wm4[j], xv);
                dw  += dot4(ww4[j], xv);
            }
            lrS[l] = softplusf(dlr);
            float lm = -softplusf(-dm);   // log sigmoid
            float lw = -softplusf(-dw);
            lwS[l]  = lw;
            clmS[l] = lm;
            cwdS[l] = lw;
        }
        __syncthreads();
        for (int off = 1; off < Lc; off <<= 1) {
            float a = 0.f, c = 0.f;
            if (l < Lc && l >= off) { a = clmS[l - off]; c = cwdS[l - off]; }
            __syncthreads();
            if (l < Lc) { clmS[l] += a; cwdS[l] += c; }
            __syncthreads();
        }
        if (l < Lc) {
            wdf[b * Lc + l] = expf(cwdS[l]);
            ewdS[l] = __expf(lwS[l]);
        }
        __syncthreads();
        if (l < Lc) {
            // S[l,m] recurrence, thread = m; batch-8 pipelined.
            const int   m     = l;
            const float clm_m = clmS[m];
            const float lrm   = lrS[m];
            float* outp = Ssc + (b * Lc) * Lc + m;
            const int ll0 = m & ~63;      // wave-uniform causal start
            {
                int zs = m - 3 < 0 ? 0 : m - 3;
                for (int ll = zs; ll < ll0; ++ll) outp[ll * Lc] = 0.f;
            }
            float s = 0.f;
            for (int ll4 = ll0; ll4 < Lc; ll4 += 8) {
                float4 cla = *(const float4*)&clmS[ll4];
                float4 clb = *(const float4*)&clmS[ll4 + 4];
                float4 ewa = *(const float4*)&ewdS[ll4];
                float4 ewb = *(const float4*)&ewdS[ll4 + 4];
                float ew[8] = {ewa.x, ewa.y, ewa.z, ewa.w,
                               ewb.x, ewb.y, ewb.z, ewb.w};
                float e2[8];
                e2[0] = __expf(cla.x - clm_m); e2[1] = __expf(cla.y - clm_m);
                e2[2] = __expf(cla.z - clm_m); e2[3] = __expf(cla.w - clm_m);
                e2[4] = __expf(clb.x - clm_m); e2[5] = __expf(clb.y - clm_m);
                e2[6] = __expf(clb.z - clm_m); e2[7] = __expf(clb.w - clm_m);
                #pragma unroll
                for (int u = 0; u < 8; ++u) {
                    const int ll = ll4 + u;
                    s = (ll >= m) ? (ew[u] * s + e2[u]) : 0.f;
                    outp[ll * Lc] = s * lrm;
                }
            }
        }
        return;
    }

    // ================= token work: 2 tokens/block, 1024 threads ============
    __shared__ __align__(16) float xs[2][Dc], qs[2][Dc], ks[2][Dc], vs[2][Dc];
    __shared__ __align__(16) float X2s[2][Hc], z1s[2][Hc], gZ2s[2][Dc];
    __shared__ __align__(16) float pqk[4][2][Dc];   // q-lo,q-hi,k-lo,k-hi
    __shared__ __align__(16) float pv4[4][2][Dc];
    __shared__ __align__(16) float p2[4][2][Hc];    // (srcq + 2*dhalf)
    __shared__ __align__(16) float pz8[8][2][Dc];
    __shared__ __align__(16) float pg4[4][2][Hc];

    const int t0 = bb * 2;
    const int b  = t0 >> 8;
    const int l0 = t0 & 255;

    if (tid < 2 * Dc / 4)
        ((float4*)&xs[0][0])[tid] = ((const float4*)(x + t0 * Dc))[tid];
    __syncthreads();

    // --- phase 1: 8 groups of 128: q-lo,q-hi,k-lo,k-hi, v-quarters ---
    {
        const int g = tid >> 7, c = tid & 127;
        if (g < 4) {
            const int isK = g >> 1, dh = g & 1;
            const float4* W = isK ? Wk4 : Wq4;
            const int j0 = dh * 16;
            float a0 = 0.f, a1 = 0.f;
            float4 wb[16];
            #pragma unroll
            for (int u = 0; u < 16; ++u) wb[u] = W[(j0+u) * Dc + c];
            #pragma unroll
            for (int u = 0; u < 16; ++u) {
                a0 += dot4(wb[u], *(const float4*)&xs[0][4*(j0+u)]);
                a1 += dot4(wb[u], *(const float4*)&xs[1][4*(j0+u)]);
            }
            pqk[g][0][c] = a0; pqk[g][1][c] = a1;
        } else {
            const int qtr = g - 4, j0 = qtr * 8;
            float a0 = 0.f, a1 = 0.f;
            float4 wb[8];
            #pragma unroll
            for (int u = 0; u < 8; ++u) wb[u] = Wv4[(j0+u) * Dc + c];
            #pragma unroll
            for (int u = 0; u < 8; ++u) {
                a0 += dot4(wb[u], *(const float4*)&xs[0][4*(j0+u)]);
                a1 += dot4(wb[u], *(const float4*)&xs[1][4*(j0+u)]);
            }
            pv4[qtr][0][c] = a0; pv4[qtr][1][c] = a1;
        }
    }
    __syncthreads();
    if (tid < 256) {                  // q combine
        const int t = tid >> 7, c = tid & 127;
        float v = pqk[0][t][c] + pqk[1][t][c] + bq[c];
        qs[t][c] = v;
        qo[(t0 + t) * Dc + c] = v;
    } else if (tid < 512) {           // k combine (+ KT store)
        const int i = tid - 256, t = i >> 7, c = i & 127;
        float v = pqk[2][t][c] + pqk[3][t][c] + bk[c];
        ks[t][c] = v;
        KT[(size_t)b * 32768 + ((c >> 2) * Lc + l0 + t) * 4 + (c & 3)] = v;
    } else if (tid < 768) {           // v combine
        const int i = tid - 512, t = i >> 7, c = i & 127;
        vs[t][c] = pv4[0][t][c] + pv4[1][t][c] + pv4[2][t][c]
                 + pv4[3][t][c] + bv[c];
    }
    __syncthreads();

    // --- phase 2: 4 groups of 256: (k|q) x (d-lo|d-hi) ---
    {
        const int which = tid >> 8, h = tid & 255;
        const int srcq = which & 1, dh = which >> 1;
        const float (*src)[Dc] = srcq ? qs : ks;
        const int d0 = dh * 16;
        float a0 = 0.f, a1 = 0.f;
        float4 wb[16];
        #pragma unroll
        for (int u = 0; u < 16; ++u) wb[u] = W14[(d0+u) * Hc + h];
        #pragma unroll
        for (int u = 0; u < 16; ++u) {
            a0 += dot4(wb[u], *(const float4*)&src[0][4*(d0+u)]);
            a1 += dot4(wb[u], *(const float4*)&src[1][4*(d0+u)]);
        }
        p2[which][0][h] = a0; p2[which][1][h] = a1;
    }
    __syncthreads();
    {
        const int sel = tid >> 9, i = tid & 511, t = i >> 8, h = i & 255;
        if (sel == 0) {               // Z1 -> silu -> X2 (+ X2T store)
            float z = p2[0][t][h] + p2[2][t][h] + b1v[h];
            z1s[t][h] = z;
            float s = siluf(z);
            X2s[t][h] = s;
            X2T[(size_t)b * 65536 + ((h >> 2) * Lc + l0 + t) * 4 + (h & 3)] = s;
        } else {                      // z1q
            z1q[(t0 + t) * Hc + h] = p2[1][t][h] + p2[3][t][h] + b1v[h];
        }
    }
    __syncthreads();

    // --- phase 3: Z2, 8 groups of 128 over h-eighths ---
    {
        const int g = tid >> 7, d = tid & 127;
        const int h0 = g * 8;
        float a0 = 0.f, a1 = 0.f;
        float4 wb[8];
        #pragma unroll
        for (int u = 0; u < 8; ++u) wb[u] = W2q4[(h0+u) * Dc + d];
        #pragma unroll
        for (int u = 0; u < 8; ++u) {
            a0 += dot4(wb[u], *(const float4*)&X2s[0][4*(h0+u)]);
            a1 += dot4(wb[u], *(const float4*)&X2s[1][4*(h0+u)]);
        }
        pz8[g][0][d] = a0; pz8[g][1][d] = a1;
    }
    __syncthreads();
    if (tid < 256) {
        const int t = tid >> 7, d = tid & 127;
        float g = pz8[0][t][d] + pz8[1][t][d] + pz8[2][t][d] + pz8[3][t][d]
                + pz8[4][t][d] + pz8[5][t][d] + pz8[6][t][d] + pz8[7][t][d]
                + b2v[d] - vs[t][d];
        gZ2s[t][d] = g;
        const int l = l0 + t;
        GZ2[(size_t)b * 32768 + ((l >> 2) * Dc + d) * 4 + (l & 3)] = g;
    }
    __syncthreads();

    // --- phase 4: gX2, 4 groups of 256 over d-quarters ---
    {
        const int g = tid >> 8, h = tid & 255;
        const int d0 = g * 8;
        float a0 = 0.f, a1 = 0.f;
        float4 wb[8];
        #pragma unroll
        for (int u = 0; u < 8; ++u) wb[u] = W2c4[(d0+u) * Hc + h];
        #pragma unroll
        for (int u = 0; u < 8; ++u) {
            a0 += dot4(wb[u], *(const float4*)&gZ2s[0][4*(d0+u)]);
            a1 += dot4(wb[u], *(const float4*)&gZ2s[1][4*(d0+u)]);
        }
        pg4[g][0][h] = a0; pg4[g][1][h] = a1;
    }
    __syncthreads();
    if (tid < 512) {
        const int t = tid >> 8, h = tid & 255;
        const int l = l0 + t;
        float a = pg4[0][t][h] + pg4[1][t][h] + pg4[2][t][h] + pg4[3][t][h];
        GZ1[(size_t)b * 65536 + ((l >> 2) * Hc + h) * 4 + (l & 3)]
            = a * silubwdf(z1s[t][h]);
    }
}

// ---------------------------------------------------------------------------
// K2: fused query. 256 blocks x 1024 threads, 2 tokens/block; causal-bounded.
// ---------------------------------------------------------------------------
__global__ __launch_bounds__(1024, 4) void k_query(
    const float* __restrict__ qo,  const float* __restrict__ KT,
    const float* __restrict__ X2T, const float* __restrict__ GZ1,
    const float* __restrict__ GZ2, const float* __restrict__ z1q,
    const float* __restrict__ Ssc, const float* __restrict__ wdf,
    const float4* __restrict__ W2q4, const float* __restrict__ b2v,
    float* __restrict__ out)
{
    __shared__ __align__(16) float qs[2][Dc], ss[2][Lc], arow[2][Lc], xq2s[2][Hc];
    __shared__ __align__(16) float psc[4][2][Lc];   // score partials
    __shared__ __align__(16) float pzq[4][2][Hc];   // Zq1 partials
    __shared__ __align__(16) float pm4[4][2][Dc], pw4[4][2][Dc];

    const int t0  = blockIdx.x * 2;
    const int b   = t0 >> 8;
    const int l0  = t0 & 255;
    const int tid = threadIdx.x;
    const int M4  = ((l0 + 1) >> 2) + 1;   // causal bound for the PAIR (exact:
    const int mPad = M4 * 4;               // ss is zero above each row's diag)

    if (tid < 2 * Dc / 4)
        ((float4*)&qs[0][0])[tid] = ((const float4*)(qo + t0 * Dc))[tid];
    if (tid >= 512 && tid < 1024) {
        const int i = tid - 512, t = i >> 8, m = i & 255;
        ss[t][m] = Ssc[(t0 + t) * Lc + m];
    }
    const float wdf0 = wdf[t0 + 0], wdf1 = wdf[t0 + 1];
    __syncthreads();

    // --- score1 partials: 4 d-quarters, both tokens per load ---
    {
        const int which = tid >> 8, m = tid & 255;
        if (m < mPad) {
            const float4* ktb = (const float4*)(KT + (size_t)b * 32768);
            const int d0 = which * 8;
            float acc0 = 0.f, acc1 = 0.f;
            float4 wb[8];
            #pragma unroll
            for (int u = 0; u < 8; ++u) wb[u] = ktb[(d0+u) * Lc + m];
            #pragma unroll
            for (int u = 0; u < 8; ++u) {
                acc0 += dot4(wb[u], *(const float4*)&qs[0][4*(d0+u)]);
                acc1 += dot4(wb[u], *(const float4*)&qs[1][4*(d0+u)]);
            }
            psc[which][0][m] = acc0; psc[which][1][m] = acc1;
        }
    }
    __syncthreads();
    if (tid < 512) {
        const int t = tid >> 8, m = tid & 255;
        if (m < mPad)
            arow[t][m] = ss[t][m] * (psc[0][t][m] + psc[1][t][m]
                                   + psc[2][t][m] + psc[3][t][m] + 1.f);
    }
    __syncthreads();

    // --- Zq1 partials: 4-way strided m4-split, both tokens per load ---
    {
        const int which = tid >> 8, h = tid & 255;
        const float4* g = (const float4*)(GZ1 + (size_t)b * 65536);
        const float4* ar0 = (const float4*)&arow[0][0];
        const float4* ar1 = (const float4*)&arow[1][0];
        float acc0 = 0.f, acc1 = 0.f;
        float4 wb[16];
        int m4 = which;
        for (; m4 + 60 < M4; m4 += 64) {
            #pragma unroll
            for (int u = 0; u < 16; ++u) wb[u] = g[(m4 + 4*u) * Hc + h];
            #pragma unroll
            for (int u = 0; u < 16; ++u) {
                acc0 += dot4(wb[u], ar0[m4 + 4*u]);
                acc1 += dot4(wb[u], ar1[m4 + 4*u]);
            }
        }
        for (; m4 < M4; m4 += 4) {
            float4 gv = g[m4 * Hc + h];
            acc0 += dot4(gv, ar0[m4]);
            acc1 += dot4(gv, ar1[m4]);
        }
        pzq[which][0][h] = acc0; pzq[which][1][h] = acc1;
    }
    __syncthreads();
    if (tid < 512) {
        const int t = tid >> 8, h = tid & 255;
        const float w = t ? wdf1 : wdf0;
        xq2s[t][h] = siluf(pzq[0][t][h] + pzq[1][t][h] + pzq[2][t][h]
                           + pzq[3][t][h] + w * z1q[(t0 + t) * Hc + h]);
    }
    __syncthreads();

    // --- score2 partials: 4 h-quarters, both tokens per load ---
    {
        const int which = tid >> 8, m = tid & 255;
        if (m < mPad) {
            const float4* xtb = (const float4*)(X2T + (size_t)b * 65536);
            const int h0 = which * 16;
            float acc0 = 0.f, acc1 = 0.f;
            float4 wb[16];
            #pragma unroll
            for (int u = 0; u < 16; ++u) wb[u] = xtb[(h0+u) * Lc + m];
            #pragma unroll
            for (int u = 0; u < 16; ++u) {
                acc0 += dot4(wb[u], *(const float4*)&xq2s[0][4*(h0+u)]);
                acc1 += dot4(wb[u], *(const float4*)&xq2s[1][4*(h0+u)]);
            }
            psc[which][0][m] = acc0; psc[which][1][m] = acc1;
        }
    }
    __syncthreads();
    if (tid < 512) {
        const int t = tid >> 8, m = tid & 255;
        if (m < mPad)
            arow[t][m] = ss[t][m] * (psc[0][t][m] + psc[1][t][m]
                                   + psc[2][t][m] + psc[3][t][m] + 1.f);
    }
    __syncthreads();

    // --- Zq2: 8 groups of 128 (4 m-strided + 4 h-chunks) ---
    {
        const int g8 = tid >> 7, d = tid & 127;
        if (g8 < 4) {
            const float4* g2  = (const float4*)(GZ2 + (size_t)b * 32768);
            const float4* ar0 = (const float4*)&arow[0][0];
            const float4* ar1 = (const float4*)&arow[1][0];
            float am0 = 0.f, am1 = 0.f;
            float4 wb[16];
            int m4 = g8;
            for (; m4 + 60 < M4; m4 += 64) {
                #pragma unroll
                for (int u = 0; u < 16; ++u) wb[u] = g2[(m4 + 4*u) * Dc + d];
                #pragma unroll
                for (int u = 0; u < 16; ++u) {
                    am0 += dot4(wb[u], ar0[m4 + 4*u]);
                    am1 += dot4(wb[u], ar1[m4 + 4*u]);
                }
            }
            for (; m4 < M4; m4 += 4) {
                float4 gv = g2[m4 * Dc + d];
                am0 += dot4(gv, ar0[m4]);
                am1 += dot4(gv, ar1[m4]);
            }
            pm4[g8][0][d] = am0; pm4[g8][1][d] = am1;
        } else {
            const int h0 = (g8 - 4) * 16;
            float aw0 = 0.f, aw1 = 0.f;
            float4 wb[16];
            #pragma unroll
            for (int u = 0; u < 16; ++u) wb[u] = W2q4[(h0+u) * Dc + d];
            #pragma unroll
            for (int u = 0; u < 16; ++u) {
                aw0 += dot4(wb[u], *(const float4*)&xq2s[0][4*(h0+u)]);
                aw1 += dot4(wb[u], *(const float4*)&xq2s[1][4*(h0+u)]);
            }
            pw4[g8 - 4][0][d] = aw0; pw4[g8 - 4][1][d] = aw1;
        }
    }
    __syncthreads();
    if (tid < 2 * Dc) {
        const int t = tid >> 7, d = tid & 127;
        const float w = t ? wdf1 : wdf0;
        out[(t0 + t) * Dc + d] =
            (pm4[0][t][d] + pm4[1][t][d] + pm4[2][t][d] + pm4[3][t][d])
            + w * (b2v[d] + pw4[0][t][d] + pw4[1][t][d]
                          + pw4[2][t][d] + pw4[3][t][d]);
    }
}

// ---------------------------------------------------------------------------
extern "C" void kernel_launch(void* const* d_in, const int* in_sizes, int n_in,
                              void* d_out, int out_size, void* d_ws, size_t ws_size,
                              hipStream_t stream)
{
    const float* x   = (const float*)d_in[0];
    const float* W1  = (const float*)d_in[1];
    const float* b1  = (const float*)d_in[2];
    const float* W2  = (const float*)d_in[3];
    const float* b2  = (const float*)d_in[4];
    const float* Wq  = (const float*)d_in[5];
    const float* bq  = (const float*)d_in[6];
    const float* Wk  = (const float*)d_in[7];
    const float* bk  = (const float*)d_in[8];
    const float* Wv  = (const float*)d_in[9];
    const float* bv  = (const float*)d_in[10];
    const float* Wlr = (const float*)d_in[11];
    const float* blr = (const float*)d_in[12];
    const float* Wm  = (const float*)d_in[13];
    const float* bm  = (const float*)d_in[14];
    const float* Wwd = (const float*)d_in[15];
    const float* bwd = (const float*)d_in[16];

    float* ws = (float*)d_ws;
    float*  qo   = ws;                       // 65536
    float*  KT   = ws + 65536;               // 65536
    float*  X2T  = ws + 131072;              // 131072
    float*  GZ1  = ws + 262144;              // 131072
    float*  GZ2  = ws + 393216;              // 65536
    float*  z1q  = ws + 458752;              // 131072
    float*  Ssc  = ws + 589824;              // 131072
    float*  wdf  = ws + 720896;              // 512
    float4* Wq4  = (float4*)(ws + 721408);   // 16384 floats
    float4* Wk4  = (float4*)(ws + 737792);
    float4* Wv4  = (float4*)(ws + 754176);
    float4* W14  = (float4*)(ws + 770560);   // 32768
    float4* W2q4 = (float4*)(ws + 803328);   // 32768
    float4* W2c4 = (float4*)(ws + 836096);   // 32768
    float*  out  = (float*)d_out;

    k_pre<<<144, 256, 0, stream>>>(Wq, Wk, Wv, W1, W2,
                                   Wq4, Wk4, Wv4, W14, W2q4, W2c4);
    k_token<<<Bc * Lc / 2 + Bc, 1024, 0, stream>>>(x, b1, b2, bq, bk, bv,
                                                   Wq4, Wk4, Wv4, W14, W2q4, W2c4,
                                                   Wlr, blr, Wm, bm, Wwd, bwd,
                                                   qo, KT, X2T, z1q, GZ1, GZ2,
                                                   Ssc, wdf);
    k_query<<<Bc * Lc / 2, 1024, 0, stream>>>(qo, KT, X2T, GZ1, GZ2, z1q,
                                              Ssc, wdf, W2q4, b2, out);
}

// Round 14
// 124.789 us; speedup vs baseline: 1.0242x; 1.0242x over previous
//
#include <hip/hip_runtime.h>
#include <hip/hip_bf16.h>

// B=2, L=256, D=128, H=256 fast-weight (TTT-style) forward.
// Exact rewrite: sequential momentum/weight-decay scan -> decay-weighted
// attention with composed decay matrix S = wd_cs @ mom_cs via the stable
// O(L^2) recurrence (all exponents <= 0 in the live region).
//
// v14 = v12 (best measured: 127.1us). Locked-in configuration:
//  - k_pre: coalesced weight interleave (144 blocks).
//  - k_token: 2 tokens/block, 512 threads, 2 blocks/CU (16 waves/CU),
//    wb[16] prefetch batches; gate/decay scan in blocks 256/257 with
//    batch-8 pipelined recurrence + wave-causal start.
//  - k_query: fused score1->Zq1->silu->score2->Zq2, causal-bounded m-loops.
// Per-iteration budget: ~74us harness-fixed (256MB ws re-poison at the
// ~6.3TB/s HBM ceiling + restores) + ~53us kernels (vs ~15us L2/launch
// floor; remaining gap needs MFMA-bf16 scores, too tight for the 2% abs
// threshold, or per-kernel counters the fill-flooded top-5 can't give).

#define Bc 2
#define Lc 256
#define Dc 128
#define Hc 256

__device__ __forceinline__ float sigf(float z)  { return 1.f / (1.f + expf(-z)); }
__device__ __forceinline__ float siluf(float z) { return z * sigf(z); }
// replicates reference silu_backward exactly: s + sigmoid(z)*(1-s), s=silu(z)
__device__ __forceinline__ float silubwdf(float z) {
    float sg = sigf(z);
    float s  = z * sg;
    return s + sg * (1.f - s);
}
__device__ __forceinline__ float softplusf(float z) {
    if (z > 20.f)  return z;
    if (z < -20.f) return expf(z);
    return log1pf(expf(z));
}
__device__ __forceinline__ float dot4(float4 a, float4 b) {
    return a.x*b.x + a.y*b.y + a.z*b.z + a.w*b.w;
}

// ---------------------------------------------------------------------------
// K0: pure weight interleave, 144 blocks x 256 threads.
// ---------------------------------------------------------------------------
__global__ __launch_bounds__(256) void k_pre(
    const float* __restrict__ Wq, const float* __restrict__ Wk,
    const float* __restrict__ Wv, const float* __restrict__ W1,
    const float* __restrict__ W2,
    float4* __restrict__ Wq4, float4* __restrict__ Wk4, float4* __restrict__ Wv4,
    float4* __restrict__ W14, float4* __restrict__ W2q4, float4* __restrict__ W2c4)
{
    const int bb = blockIdx.x;
    if (bb < 112) {
        const float* in; float4* o; int M, N, base;
        if      (bb < 16) { in = Wq; o = Wq4;  M = 128; N = 128; base = 0;  }
        else if (bb < 32) { in = Wk; o = Wk4;  M = 128; N = 128; base = 16; }
        else if (bb < 48) { in = Wv; o = Wv4;  M = 128; N = 128; base = 32; }
        else if (bb < 80) { in = W1; o = W14;  M = 256; N = 128; base = 48; }
        else              { in = W2; o = W2q4; M = 128; N = 256; base = 80; }
        const int idx = (bb - base) * 256 + threadIdx.x;
        const int r = idx % M, g = idx / M;
        o[idx] = *(const float4*)(in + r * N + 4 * g);
    } else {
        const int idx = (bb - 112) * 256 + threadIdx.x;   // 0..8191
        const int c = idx & 255, g = idx >> 8;
        W2c4[idx] = make_float4(W2[(4*g+0)*Hc + c], W2[(4*g+1)*Hc + c],
                                W2[(4*g+2)*Hc + c], W2[(4*g+3)*Hc + c]);
    }
}

// ---------------------------------------------------------------------------
// K1: token fwd + grads (blocks 0..255, 2 tokens/block) +
//     gate/decay scan (blocks 256/257, one per batch).
// ---------------------------------------------------------------------------
__global__ __launch_bounds__(512, 4) void k_token(
    const float* __restrict__ x,
    const float* __restrict__ b1v, const float* __restrict__ b2v,
    const float* __restrict__ bq,  const float* __restrict__ bk,
    const float* __restrict__ bv,
    const float4* __restrict__ Wq4, const float4* __restrict__ Wk4,
    const float4* __restrict__ Wv4, const float4* __restrict__ W14,
    const float4* __restrict__ W2q4, const float4* __restrict__ W2c4,
    const float* __restrict__ Wlr, const float* __restrict__ blr,
    const float* __restrict__ Wm,  const float* __restrict__ bm,
    const float* __restrict__ Wwd, const float* __restrict__ bwd,
    float* __restrict__ qo, float* __restrict__ KT, float* __restrict__ X2T,
    float* __restrict__ z1q, float* __restrict__ GZ1, float* __restrict__ GZ2,
    float* __restrict__ Ssc, float* __restrict__ wdf)
{
    const int bb  = blockIdx.x;
    const int tid = threadIdx.x;

    if (bb >= Bc * Lc / 2) {
        // ================= gate/decay scan (1 block per batch) =============
        __shared__ __align__(16) float lrS[Lc];
        __shared__ __align__(16) float lwS[Lc];
        __shared__ __align__(16) float ewdS[Lc];
        __shared__ __align__(16) float clmS[Lc];
        __shared__ __align__(16) float cwdS[Lc];
        const int b = bb - Bc * Lc / 2;
        const int l = tid;
        if (l < Lc) {
            const float4* xr4 = (const float4*)(x + (b * Lc + l) * Dc);
            const float4* wl4 = (const float4*)Wlr;
            const float4* wm4 = (const float4*)Wm;
            const float4* ww4 = (const float4*)Wwd;
            float dlr = blr[0], dm = bm[0], dw = bwd[0];
            #pragma unroll 4
            for (int j = 0; j < Dc / 4; ++j) {
                float4 xv = xr4[j];
                dlr += dot4(wl4[j], xv);
                dm  += dot4(wm4[j], xv);
                dw  += dot4(ww4[j], xv);
            }
            lrS[l] = softplusf(dlr);
            float lm = -softplusf(-dm);   // log sigmoid
            float lw = -softplusf(-dw);
            lwS[l]  = lw;
            clmS[l] = lm;
            cwdS[l] = lw;
        }
        __syncthreads();
        for (int off = 1; off < Lc; off <<= 1) {
            float a = 0.f, c = 0.f;
            if (l < Lc && l >= off) { a = clmS[l - off]; c = cwdS[l - off]; }
            __syncthreads();
            if (l < Lc) { clmS[l] += a; cwdS[l] += c; }
            __syncthreads();
        }
        if (l < Lc) {
            wdf[b * Lc + l] = expf(cwdS[l]);
            ewdS[l] = __expf(lwS[l]);
        }
        __syncthreads();
        if (l < Lc) {
            // S[l,m] recurrence, thread = m; batch-8 pipelined.
            const int   m     = l;
            const float clm_m = clmS[m];
            const float lrm   = lrS[m];
            float* outp = Ssc + (b * Lc) * Lc + m;
            const int ll0 = m & ~63;      // wave-uniform causal start
            {
                int zs = m - 3 < 0 ? 0 : m - 3;
                for (int ll = zs; ll < ll0; ++ll) outp[ll * Lc] = 0.f;
            }
            float s = 0.f;
            for (int ll4 = ll0; ll4 < Lc; ll4 += 8) {
                float4 cla = *(const float4*)&clmS[ll4];
                float4 clb = *(const float4*)&clmS[ll4 + 4];
                float4 ewa = *(const float4*)&ewdS[ll4];
                float4 ewb = *(const float4*)&ewdS[ll4 + 4];
                float ew[8] = {ewa.x, ewa.y, ewa.z, ewa.w,
                               ewb.x, ewb.y, ewb.z, ewb.w};
                float e2[8];
                e2[0] = __expf(cla.x - clm_m); e2[1] = __expf(cla.y - clm_m);
                e2[2] = __expf(cla.z - clm_m); e2[3] = __expf(cla.w - clm_m);
                e2[4] = __expf(clb.x - clm_m); e2[5] = __expf(clb.y - clm_m);
                e2[6] = __expf(clb.z - clm_m); e2[7] = __expf(clb.w - clm_m);
                #pragma unroll
                for (int u = 0; u < 8; ++u) {
                    const int ll = ll4 + u;
                    s = (ll >= m) ? (ew[u] * s + e2[u]) : 0.f;
                    outp[ll * Lc] = s * lrm;
                }
            }
        }
        return;
    }

    // ================= token work: 2 tokens/block ==========================
    __shared__ __align__(16) float xs[2][Dc], qs[2][Dc], ks[2][Dc];
    __shared__ __align__(16) float X2s[2][Hc], z1s[2][Hc], gZ2s[2][Dc];
    __shared__ __align__(16) float pv[2][2][Dc], pz[4][2][Dc], pg[2][2][Hc];

    const int t0 = bb * 2;
    const int b  = t0 >> 8;
    const int l0 = t0 & 255;

    if (tid < 2 * Dc / 4)
        ((float4*)&xs[0][0])[tid] = ((const float4*)(x + t0 * Dc))[tid];
    __syncthreads();

    // --- phase 1: g0=q, g1=k, g2/g3=v halves; each load feeds both tokens ---
    {
        const int g = tid >> 7, c = tid & 127;
        float4 wb[16];
        if (g < 2) {
            const float4* W = g ? Wk4 : Wq4;
            float a0 = (g ? bk : bq)[c], a1 = a0;
            for (int j4 = 0; j4 < 32; j4 += 16) {
                #pragma unroll
                for (int u = 0; u < 16; ++u) wb[u] = W[(j4+u) * Dc + c];
                #pragma unroll
                for (int u = 0; u < 16; ++u) {
                    a0 += dot4(wb[u], *(const float4*)&xs[0][4*(j4+u)]);
                    a1 += dot4(wb[u], *(const float4*)&xs[1][4*(j4+u)]);
                }
            }
            if (g == 0) {
                qs[0][c] = a0; qs[1][c] = a1;
                qo[t0 * Dc + c] = a0;
                qo[(t0 + 1) * Dc + c] = a1;
            } else {
                ks[0][c] = a0; ks[1][c] = a1;
                float* ktp = KT + (size_t)b * 32768;
                ktp[((c >> 2) * Lc + l0 + 0) * 4 + (c & 3)] = a0;
                ktp[((c >> 2) * Lc + l0 + 1) * 4 + (c & 3)] = a1;
            }
        } else {
            const int half = g - 2, j0 = half * 16;
            float av0 = 0.f, av1 = 0.f;
            #pragma unroll
            for (int u = 0; u < 16; ++u) wb[u] = Wv4[(j0+u) * Dc + c];
            #pragma unroll
            for (int u = 0; u < 16; ++u) {
                av0 += dot4(wb[u], *(const float4*)&xs[0][4*(j0+u)]);
                av1 += dot4(wb[u], *(const float4*)&xs[1][4*(j0+u)]);
            }
            pv[half][0][c] = av0; pv[half][1][c] = av1;
        }
    }
    __syncthreads();

    // --- phase 2: which=0 -> Z1 (from k), which=1 -> z1q (from q) ---
    {
        const int which = tid >> 8, h = tid & 255;
        const float (*src)[Dc] = which ? qs : ks;
        float a0 = b1v[h], a1 = a0;
        float4 wb[16];
        for (int d4 = 0; d4 < 32; d4 += 16) {
            #pragma unroll
            for (int u = 0; u < 16; ++u) wb[u] = W14[(d4+u) * Hc + h];
            #pragma unroll
            for (int u = 0; u < 16; ++u) {
                a0 += dot4(wb[u], *(const float4*)&src[0][4*(d4+u)]);
                a1 += dot4(wb[u], *(const float4*)&src[1][4*(d4+u)]);
            }
        }
        if (which == 0) {
            z1s[0][h] = a0; z1s[1][h] = a1;
            float s0 = siluf(a0), s1 = siluf(a1);
            X2s[0][h] = s0; X2s[1][h] = s1;
            float* xtp = X2T + (size_t)b * 65536;
            xtp[((h >> 2) * Lc + l0 + 0) * 4 + (h & 3)] = s0;
            xtp[((h >> 2) * Lc + l0 + 1) * 4 + (h & 3)] = s1;
        } else {
            z1q[(t0 + 0) * Hc + h] = a0;
            z1q[(t0 + 1) * Hc + h] = a1;
        }
    }
    __syncthreads();

    // --- phase 3: Z2 4-way h-split, both tokens per load ---
    {
        const int q4g = tid >> 7, d = tid & 127;
        const int h0 = q4g * 16;
        float a0 = 0.f, a1 = 0.f;
        float4 wb[16];
        #pragma unroll
        for (int u = 0; u < 16; ++u) wb[u] = W2q4[(h0+u) * Dc + d];
        #pragma unroll
        for (int u = 0; u < 16; ++u) {
            a0 += dot4(wb[u], *(const float4*)&X2s[0][4*(h0+u)]);
            a1 += dot4(wb[u], *(const float4*)&X2s[1][4*(h0+u)]);
        }
        pz[q4g][0][d] = a0; pz[q4g][1][d] = a1;
    }
    __syncthreads();
    if (tid < 2 * Dc) {
        const int t = tid >> 7, d = tid & 127;
        float g = pz[0][t][d] + pz[1][t][d] + pz[2][t][d] + pz[3][t][d] + b2v[d]
                - (pv[0][t][d] + pv[1][t][d] + bv[d]);
        gZ2s[t][d] = g;
        const int l = l0 + t;
        GZ2[(size_t)b * 32768 + ((l >> 2) * Dc + d) * 4 + (l & 3)] = g;
    }
    __syncthreads();

    // --- phase 4: gX2 2-way d-split; gZ1 = gX2 * silu_bwd(Z1) ---
    {
        const int which = tid >> 8, h = tid & 255;
        const int d0 = which * 16;
        float a0 = 0.f, a1 = 0.f;
        float4 wb[16];
        #pragma unroll
        for (int u = 0; u < 16; ++u) wb[u] = W2c4[(d0+u) * Hc + h];
        #pragma unroll
        for (int u = 0; u < 16; ++u) {
            a0 += dot4(wb[u], *(const float4*)&gZ2s[0][4*(d0+u)]);
            a1 += dot4(wb[u], *(const float4*)&gZ2s[1][4*(d0+u)]);
        }
        pg[which][0][h] = a0; pg[which][1][h] = a1;
    }
    __syncthreads();
    {
        const int t = tid >> 8, h = tid & 255;
        const int l = l0 + t;
        GZ1[(size_t)b * 65536 + ((l >> 2) * Hc + h) * 4 + (l & 3)]
            = (pg[0][t][h] + pg[1][t][h]) * silubwdf(z1s[t][h]);
    }
}

// ---------------------------------------------------------------------------
// K2: fused query. 256 blocks x 512 threads, 2 tokens/block; causal-bounded.
// ---------------------------------------------------------------------------
__global__ __launch_bounds__(512, 4) void k_query(
    const float* __restrict__ qo,  const float* __restrict__ KT,
    const float* __restrict__ X2T, const float* __restrict__ GZ1,
    const float* __restrict__ GZ2, const float* __restrict__ z1q,
    const float* __restrict__ Ssc, const float* __restrict__ wdf,
    const float4* __restrict__ W2q4, const float* __restrict__ b2v,
    float* __restrict__ out)
{
    __shared__ __align__(16) float qs[2][Dc], ss[2][Lc], arow[2][Lc], xq2s[2][Hc];
    __shared__ __align__(16) float ps[2][2][Lc], pq[2][2][Hc];
    __shared__ __align__(16) float pm[4][2][Dc], pw[4][2][Dc];

    const int t0  = blockIdx.x * 2;
    const int b   = t0 >> 8;
    const int l0  = t0 & 255;
    const int tid = threadIdx.x;
    const int M4  = ((l0 + 1) >> 2) + 1;   // causal bound for the PAIR (exact:
    const int mPad = M4 * 4;               // ss is zero above each row's diag)

    if (tid < 2 * Dc / 4)
        ((float4*)&qs[0][0])[tid] = ((const float4*)(qo + t0 * Dc))[tid];
    if (tid < Lc) {
        ss[0][tid] = Ssc[(t0 + 0) * Lc + tid];
        ss[1][tid] = Ssc[(t0 + 1) * Lc + tid];
    }
    const float wdf0 = wdf[t0 + 0], wdf1 = wdf[t0 + 1];
    __syncthreads();

    // --- score1 partials: 2-way d-split, both tokens per load ---
    {
        const int which = tid >> 8, m = tid & 255;
        if (m < mPad) {
            const float4* ktb = (const float4*)(KT + (size_t)b * 32768);
            const int d0 = which * 16;
            float acc0 = 0.f, acc1 = 0.f;
            float4 wb[16];
            #pragma unroll
            for (int u = 0; u < 16; ++u) wb[u] = ktb[(d0+u) * Lc + m];
            #pragma unroll
            for (int u = 0; u < 16; ++u) {
                acc0 += dot4(wb[u], *(const float4*)&qs[0][4*(d0+u)]);
                acc1 += dot4(wb[u], *(const float4*)&qs[1][4*(d0+u)]);
            }
            ps[which][0][m] = acc0; ps[which][1][m] = acc1;
        }
    }
    __syncthreads();
    {
        const int t = tid >> 8, m = tid & 255;
        if (m < mPad)
            arow[t][m] = ss[t][m] * (ps[0][t][m] + ps[1][t][m] + 1.f);
    }
    __syncthreads();

    // --- Zq1 partials: 2-way strided m4-split, both tokens per load ---
    {
        const int which = tid >> 8, h = tid & 255;
        const float4* g = (const float4*)(GZ1 + (size_t)b * 65536);
        const float4* ar0 = (const float4*)&arow[0][0];
        const float4* ar1 = (const float4*)&arow[1][0];
        float acc0 = 0.f, acc1 = 0.f;
        float4 wb[16];
        int m4 = which;
        for (; m4 + 30 < M4; m4 += 32) {
            #pragma unroll
            for (int u = 0; u < 16; ++u) wb[u] = g[(m4 + 2*u) * Hc + h];
            #pragma unroll
            for (int u = 0; u < 16; ++u) {
                acc0 += dot4(wb[u], ar0[m4 + 2*u]);
                acc1 += dot4(wb[u], ar1[m4 + 2*u]);
            }
        }
        for (; m4 < M4; m4 += 2) {
            float4 gv = g[m4 * Hc + h];
            acc0 += dot4(gv, ar0[m4]);
            acc1 += dot4(gv, ar1[m4]);
        }
        pq[which][0][h] = acc0; pq[which][1][h] = acc1;
    }
    __syncthreads();
    {
        const int t = tid >> 8, h = tid & 255;
        const float w = t ? wdf1 : wdf0;
        xq2s[t][h] = siluf(pq[0][t][h] + pq[1][t][h]
                           + w * z1q[(t0 + t) * Hc + h]);
    }
    __syncthreads();

    // --- score2 partials: 2-way h-split, both tokens per load ---
    {
        const int which = tid >> 8, m = tid & 255;
        if (m < mPad) {
            const float4* xtb = (const float4*)(X2T + (size_t)b * 65536);
            const int h0 = which * 32;
            float acc0 = 0.f, acc1 = 0.f;
            float4 wb[16];
            for (int h4 = h0; h4 < h0 + 32; h4 += 16) {
                #pragma unroll
                for (int u = 0; u < 16; ++u) wb[u] = xtb[(h4+u) * Lc + m];
                #pragma unroll
                for (int u = 0; u < 16; ++u) {
                    acc0 += dot4(wb[u], *(const float4*)&xq2s[0][4*(h4+u)]);
                    acc1 += dot4(wb[u], *(const float4*)&xq2s[1][4*(h4+u)]);
                }
            }
            ps[which][0][m] = acc0; ps[which][1][m] = acc1;
        }
    }
    __syncthreads();
    {
        const int t = tid >> 8, m = tid & 255;
        if (m < mPad)
            arow[t][m] = ss[t][m] * (ps[0][t][m] + ps[1][t][m] + 1.f);
    }
    __syncthreads();

    // --- Zq2: 4-way split (m-part strided m4, w-part chunked h) ---
    {
        const int q4g = tid >> 7, d = tid & 127;
        const float4* g2  = (const float4*)(GZ2 + (size_t)b * 32768);
        const float4* ar0 = (const float4*)&arow[0][0];
        const float4* ar1 = (const float4*)&arow[1][0];
        float am0 = 0.f, am1 = 0.f, aw0 = 0.f, aw1 = 0.f;
        float4 wb[16];
        int m4 = q4g;
        for (; m4 + 60 < M4; m4 += 64) {
            #pragma unroll
            for (int u = 0; u < 16; ++u) wb[u] = g2[(m4 + 4*u) * Dc + d];
            #pragma unroll
            for (int u = 0; u < 16; ++u) {
                am0 += dot4(wb[u], ar0[m4 + 4*u]);
                am1 += dot4(wb[u], ar1[m4 + 4*u]);
            }
        }
        for (; m4 < M4; m4 += 4) {
            float4 gv = g2[m4 * Dc + d];
            am0 += dot4(gv, ar0[m4]);
            am1 += dot4(gv, ar1[m4]);
        }
        const int h0 = q4g * 16;
        #pragma unroll
        for (int u = 0; u < 16; ++u) wb[u] = W2q4[(h0+u) * Dc + d];
        #pragma unroll
        for (int u = 0; u < 16; ++u) {
            aw0 += dot4(wb[u], *(const float4*)&xq2s[0][4*(h0+u)]);
            aw1 += dot4(wb[u], *(const float4*)&xq2s[1][4*(h0+u)]);
        }
        pm[q4g][0][d] = am0; pm[q4g][1][d] = am1;
        pw[q4g][0][d] = aw0; pw[q4g][1][d] = aw1;
    }
    __syncthreads();
    if (tid < 2 * Dc) {
        const int t = tid >> 7, d = tid & 127;
        const float w = t ? wdf1 : wdf0;
        out[(t0 + t) * Dc + d] =
            (pm[0][t][d] + pm[1][t][d] + pm[2][t][d] + pm[3][t][d])
            + w * (b2v[d] + pw[0][t][d] + pw[1][t][d] + pw[2][t][d] + pw[3][t][d]);
    }
}

// ---------------------------------------------------------------------------
extern "C" void kernel_launch(void* const* d_in, const int* in_sizes, int n_in,
                              void* d_out, int out_size, void* d_ws, size_t ws_size,
                              hipStream_t stream)
{
    const float* x   = (const float*)d_in[0];
    const float* W1  = (const float*)d_in[1];
    const float* b1  = (const float*)d_in[2];
    const float* W2  = (const float*)d_in[3];
    const float* b2  = (const float*)d_in[4];
    const float* Wq  = (const float*)d_in[5];
    const float* bq  = (const float*)d_in[6];
    const float* Wk  = (const float*)d_in[7];
    const float* bk  = (const float*)d_in[8];
    const float* Wv  = (const float*)d_in[9];
    const float* bv  = (const float*)d_in[10];
    const float* Wlr = (const float*)d_in[11];
    const float* blr = (const float*)d_in[12];
    const float* Wm  = (const float*)d_in[13];
    const float* bm  = (const float*)d_in[14];
    const float* Wwd = (const float*)d_in[15];
    const float* bwd = (const float*)d_in[16];

    float* ws = (float*)d_ws;
    float*  qo   = ws;                       // 65536
    float*  KT   = ws + 65536;               // 65536
    float*  X2T  = ws + 131072;              // 131072
    float*  GZ1  = ws + 262144;              // 131072
    float*  GZ2  = ws + 393216;              // 65536
    float*  z1q  = ws + 458752;              // 131072
    float*  Ssc  = ws + 589824;              // 131072
    float*  wdf  = ws + 720896;              // 512
    float4* Wq4  = (float4*)(ws + 721408);   // 16384 floats
    float4* Wk4  = (float4*)(ws + 737792);
    float4* Wv4  = (float4*)(ws + 754176);
    float4* W14  = (float4*)(ws + 770560);   // 32768
    float4* W2q4 = (float4*)(ws + 803328);   // 32768
    float4* W2c4 = (float4*)(ws + 836096);   // 32768
    float*  out  = (float*)d_out;

    k_pre<<<144, 256, 0, stream>>>(Wq, Wk, Wv, W1, W2,
                                   Wq4, Wk4, Wv4, W14, W2q4, W2c4);
    k_token<<<Bc * Lc / 2 + Bc, 512, 0, stream>>>(x, b1, b2, bq, bk, bv,
                                                  Wq4, Wk4, Wv4, W14, W2q4, W2c4,
                                                  Wlr, blr, Wm, bm, Wwd, bwd,
                                                  qo, KT, X2T, z1q, GZ1, GZ2,
                                                  Ssc, wdf);
    k_query<<<Bc * Lc / 2, 512, 0, stream>>>(qo, KT, X2T, GZ1, GZ2, z1q,
                                             Ssc, wdf, W2q4, b2, out);
}